// Round 1
// baseline (440.183 us; speedup 1.0000x reference)
//
#include <hip/hip_runtime.h>
#include <math.h>

// Problem constants (from reference setup_inputs)
#define I_DIM 512
#define J_DIM 512
#define B_DIM 4
#define NDIM  128   // hidden width
#define OPG   4     // outputs per group

// One thread per (b,i,j). Weight reads are wave-uniform (loop-counter
// indexed) -> compiler emits s_load_dwordx16; inner loop is pure v_fmac_f32
// with 128 fp32 accumulators in VGPRs. __launch_bounds__(256,2) caps VGPR
// at 256 so acc[128]+overhead (~170) never spills.
__global__ __launch_bounds__(256, 2)
void crpb_fp32_kernel(const float* __restrict__ gq,    // (512,3)
                      const float* __restrict__ gkv,   // (4,512,3)
                      const float* __restrict__ W1,    // (3,128)
                      const float* __restrict__ b1,    // (128,)
                      const float* __restrict__ W2,    // (128,128)
                      const float* __restrict__ b2,    // (128,)
                      const float* __restrict__ W3,    // (128,4)
                      const float* __restrict__ b3,    // (4,)
                      float* __restrict__ out)         // (16,512,512) flat
{
    const int flat = blockIdx.x * blockDim.x + threadIdx.x;
    const int j = flat & (J_DIM - 1);
    const int i = (flat >> 9) & (I_DIM - 1);
    const int b = flat >> 18;

    // pos = q[i] - kv[b][j]; bias = sign(pos)*log1p(|pos|)
    const float q0 = gq[i * 3 + 0];
    const float q1 = gq[i * 3 + 1];
    const float q2 = gq[i * 3 + 2];
    const int kvbase = (b * J_DIM + j) * 3;
    const float p0 = q0 - gkv[kvbase + 0];
    const float p1 = q1 - gkv[kvbase + 1];
    const float p2 = q2 - gkv[kvbase + 2];
    const float f0 = copysignf(log1pf(fabsf(p0)), p0);
    const float f1 = copysignf(log1pf(fabsf(p1)), p1);
    const float f2 = copysignf(log1pf(fabsf(p2)), p2);

    // acc[e] accumulates layer-2 pre-activation
    float acc[NDIM];
    #pragma unroll
    for (int e = 0; e < NDIM; ++e) acc[e] = b2[e];

    // Fused layer1 + layer2: h1[d] computed on the fly (1 live value),
    // rank-1 update into acc[]. W2 row-major rows -> contiguous s_loads.
    #pragma unroll 2
    for (int d = 0; d < NDIM; ++d) {
        float h = fmaf(f0, W1[0 * NDIM + d],
                  fmaf(f1, W1[1 * NDIM + d],
                  fmaf(f2, W1[2 * NDIM + d], b1[d])));
        h = fmaxf(h, 0.0f);
        const float* __restrict__ w2row = W2 + d * NDIM;
        #pragma unroll
        for (int e = 0; e < NDIM; ++e) {
            acc[e] = fmaf(h, w2row[e], acc[e]);
        }
    }

    // Layer 3: out[o] = b3[o] + sum_e relu(acc[e]) * W3[e][o]
    float o0 = b3[0], o1 = b3[1], o2 = b3[2], o3 = b3[3];
    #pragma unroll
    for (int e = 0; e < NDIM; ++e) {
        const float h2 = fmaxf(acc[e], 0.0f);
        o0 = fmaf(h2, W3[e * 4 + 0], o0);
        o1 = fmaf(h2, W3[e * 4 + 1], o1);
        o2 = fmaf(h2, W3[e * 4 + 2], o2);
        o3 = fmaf(h2, W3[e * 4 + 3], o3);
    }

    // Reference layout: out.reshape(1, B, I, J, O) -> transpose(0,1,4,2,3)
    // -> (1, B*O, I, J). Flat index: ((b*OPG + o)*I + i)*J + j.
    const size_t plane = (size_t)I_DIM * J_DIM;
    const size_t ij = (size_t)i * J_DIM + j;
    out[(size_t)(b * OPG + 0) * plane + ij] = o0;
    out[(size_t)(b * OPG + 1) * plane + ij] = o1;
    out[(size_t)(b * OPG + 2) * plane + ij] = o2;
    out[(size_t)(b * OPG + 3) * plane + ij] = o3;
}

extern "C" void kernel_launch(void* const* d_in, const int* in_sizes, int n_in,
                              void* d_out, int out_size, void* d_ws, size_t ws_size,
                              hipStream_t stream) {
    const float* gq  = (const float*)d_in[0];
    const float* gkv = (const float*)d_in[1];
    const float* W1  = (const float*)d_in[2];
    const float* b1  = (const float*)d_in[3];
    const float* W2  = (const float*)d_in[4];
    const float* b2  = (const float*)d_in[5];
    const float* W3  = (const float*)d_in[6];
    const float* b3  = (const float*)d_in[7];
    float* out = (float*)d_out;

    const int total = B_DIM * I_DIM * J_DIM;  // 1,048,576 threads
    const int block = 256;
    const int grid = total / block;           // 4096 blocks

    crpb_fp32_kernel<<<grid, block, 0, stream>>>(gq, gkv, W1, b1, W2, b2, W3, b3, out);
}

// Round 2
// 189.733 us; speedup vs baseline: 2.3200x; 2.3200x over previous
//
#include <hip/hip_runtime.h>
#include <math.h>

// ---------------- problem constants ----------------
#define I_DIM 512
#define J_DIM 512
#define B_DIM 4
#define NDIM  128            // hidden width
#define TILE  64             // positions per block-iteration (2 mtiles of 32)
#define NBLOCKS 1024
#define POS_PER_BLOCK 1024   // 1,048,576 / NBLOCKS
#define ITERS (POS_PER_BLOCK / TILE)   // 16

typedef __attribute__((ext_vector_type(8)))  short short8;    // 8 bf16 = 4 VGPRs (MFMA A/B frag)
typedef __attribute__((ext_vector_type(16))) float float16;   // MFMA C/D frag

// chunked bf16 tile: [16 kchunks][TILE pos][8 k-elems], chunk padded +8 ush
// (pad keeps 16-B alignment AND makes phase-A packed writes exactly 2-way -> free)
#define CH_STRIDE 520                 // ushorts per chunk: 64*8 + 8
#define W2_USH (16 * 128 * 8)         // 16384 ush staging: [kc][n=128][8]
#define W3_USH (16 * 32 * 8)          // 4096 ush staging: [kc][n=32 padded][8]
#define A_USH  (16 * CH_STRIDE)       // 8320 ush
#define H_USH  (16 * CH_STRIDE)       // 8320 ush
// staging (20480 ush) is dead after fragment preload; A/h2 tiles (16640 ush) alias it.
#define SMEM_USH (W2_USH + W3_USH)    // 20480 ush = 40 KB total LDS

// bf16 round-to-nearest-even, returns low 16 bits
__device__ __forceinline__ unsigned bf16r(float x) {
    unsigned u = __float_as_uint(x);
    return (u + 0x7fffu + ((u >> 16) & 1u)) >> 16;
}

__global__ __launch_bounds__(256, 2)
void crpb_mfma(const float* __restrict__ gq,   // (512,3)
               const float* __restrict__ gkv,  // (4,512,3)
               const float* __restrict__ W1,   // (3,128)
               const float* __restrict__ b1,   // (128,)
               const float* __restrict__ W2,   // (128,128)
               const float* __restrict__ b2,   // (128,)
               const float* __restrict__ W3,   // (128,4)
               const float* __restrict__ b3,   // (4,)
               float* __restrict__ out)        // (16,512,512)
{
    __shared__ unsigned short smem[SMEM_USH];
    unsigned short* w2s = smem;                // staging only
    unsigned short* w3s = smem + W2_USH;       // staging only
    unsigned short* ash = smem;                // main loop: h1 tile  [0, 8320)
    unsigned short* h2s = smem + A_USH;        // main loop: h2 tile  [8320, 16640)

    const int tid   = threadIdx.x;
    const int lane  = tid & 63;
    const int w     = tid >> 6;          // wave id 0..3
    const int l31   = lane & 31;
    const int lhalf = lane >> 5;

    // ---- stage W2 as bf16 B-frag chunks [kc][n][8] (k-major within chunk) ----
    for (int idx = tid; idx < NDIM * NDIM; idx += 256) {
        int d = idx >> 7, e = idx & 127;                    // W2[d][e], coalesced in e
        w2s[((d >> 3) * 128 + e) * 8 + (d & 7)] = (unsigned short)bf16r(W2[idx]);
    }
    // ---- stage W3 zero-padded to N=32 ----
    for (int idx = tid; idx < NDIM * 32; idx += 256) {
        int k = idx >> 5, n = idx & 31;
        unsigned short v = (n < 4) ? (unsigned short)bf16r(W3[k * 4 + n]) : (unsigned short)0;
        w3s[((k >> 3) * 32 + n) * 8 + (k & 7)] = v;
    }
    __syncthreads();

    // ---- per-lane persistent layer-1 slice: channels 2*lane, 2*lane+1 (fp32) ----
    const float w10a = W1[2 * lane],       w10b = W1[2 * lane + 1];
    const float w11a = W1[128 + 2 * lane], w11b = W1[128 + 2 * lane + 1];
    const float w12a = W1[256 + 2 * lane], w12b = W1[256 + 2 * lane + 1];
    const float b1a  = b1[2 * lane],       b1b  = b1[2 * lane + 1];

    // wave roles: ntile pair = (w&1)*2 + {0,1}; mtile = w>>1 (also phase-D mtile for waves 0,2)
    const int nt0 = (w & 1) * 2;
    const int mt  = w >> 1;
    const float b2v0 = b2[nt0 * 32 + l31];
    const float b2v1 = b2[(nt0 + 1) * 32 + l31];
    const float b3v  = (l31 < 4) ? b3[l31 & 3] : 0.0f;

    // ---- preload B-fragments into registers (W2: 64 VGPRs, W3: 32 VGPRs on waves 0,2) ----
    short8 bf0[8], bf1[8], w3f[8];
    #pragma unroll
    for (int ks = 0; ks < 8; ++ks) {
        int kc = ks * 2 + lhalf;                            // k = kc*8 + jj
        bf0[ks] = *(const short8*)&w2s[(kc * 128 + nt0 * 32 + l31) * 8];
        bf1[ks] = *(const short8*)&w2s[(kc * 128 + (nt0 + 1) * 32 + l31) * 8];
    }
    if ((w & 1) == 0) {
        #pragma unroll
        for (int ks = 0; ks < 8; ++ks) {
            int kc = ks * 2 + lhalf;
            w3f[ks] = *(const short8*)&w3s[(kc * 32 + l31) * 8];
        }
    }
    __syncthreads();   // staging region is now free to be reused as ash/h2s

    const int posblock = blockIdx.x * POS_PER_BLOCK;

    for (int it = 0; it < ITERS; ++it) {
        const int posbase = posblock + it * TILE;
        const int b     = posbase >> 18;
        const int i     = (posbase >> 9) & 511;
        const int jbase = posbase & 511;          // multiple of 64, row-aligned

        // ================= phase A: features + layer 1 (fp32) -> ash =================
        const float q0 = gq[i * 3 + 0], q1 = gq[i * 3 + 1], q2 = gq[i * 3 + 2];
        {
            // lanes 0..15 own positions w*16 + lane (others compute duplicates; no divergence)
            int jl = jbase + (w << 4) + (lane & 15);
            const float* kvp = gkv + (size_t)((b << 9) + jl) * 3;
            float d0 = q0 - kvp[0], d1 = q1 - kvp[1], d2 = q2 - kvp[2];
            float f0l = copysignf(log1pf(fabsf(d0)), d0);
            float f1l = copysignf(log1pf(fabsf(d1)), d1);
            float f2l = copysignf(log1pf(fabsf(d2)), d2);

            unsigned* au = (unsigned*)ash;
            const int base_u = (lane >> 2) * 260 + (lane & 3);   // kc = lane>>2, jj pair = lane&3
            const int posw   = (w << 4);
            #pragma unroll
            for (int pp = 0; pp < 16; ++pp) {
                float f0 = __shfl(f0l, pp);
                float f1 = __shfl(f1l, pp);
                float f2 = __shfl(f2l, pp);
                float h0  = fmaxf(fmaf(f0, w10a, fmaf(f1, w11a, fmaf(f2, w12a, b1a))), 0.f);
                float h1v = fmaxf(fmaf(f0, w10b, fmaf(f1, w11b, fmaf(f2, w12b, b1b))), 0.f);
                au[base_u + (posw + pp) * 4] = bf16r(h0) | (bf16r(h1v) << 16);
            }
        }
        __syncthreads();   // S1: ash ready (also: prior-iter h2s reads finished before C below)

        // ================= phase B: layer 2 MFMA (acc init = b2) =================
        float16 acc0, acc1;
        #pragma unroll
        for (int r = 0; r < 16; ++r) { acc0[r] = b2v0; acc1[r] = b2v1; }
        #pragma unroll
        for (int ks = 0; ks < 8; ++ks) {
            int kc = ks * 2 + lhalf;
            short8 a = *(const short8*)&ash[kc * CH_STRIDE + (mt * 32 + l31) * 8];
            acc0 = __builtin_amdgcn_mfma_f32_32x32x16_bf16(a, bf0[ks], acc0, 0, 0, 0);
            acc1 = __builtin_amdgcn_mfma_f32_32x32x16_bf16(a, bf1[ks], acc1, 0, 0, 0);
        }

        // ================= phase C: relu -> bf16 -> h2s (A-frag layout) =================
        {
            const int ch0 = nt0 * 32 + l31;
            const int ch1 = ch0 + 32;
            #pragma unroll
            for (int reg = 0; reg < 16; ++reg) {
                int r  = (reg & 3) + 8 * (reg >> 2) + 4 * lhalf;   // C/D row map (m74/m101)
                int gr = mt * 32 + r;
                h2s[(ch0 >> 3) * CH_STRIDE + gr * 8 + (ch0 & 7)] =
                    (unsigned short)bf16r(fmaxf(acc0[reg], 0.f));
                h2s[(ch1 >> 3) * CH_STRIDE + gr * 8 + (ch1 & 7)] =
                    (unsigned short)bf16r(fmaxf(acc1[reg], 0.f));
            }
        }
        __syncthreads();   // S2: h2s ready; also guarantees this iter's ash reads are done

        // ================= phase D: layer 3 MFMA + store (waves 0,2) =================
        if ((w & 1) == 0) {
            float16 acc3;
            #pragma unroll
            for (int r = 0; r < 16; ++r) acc3[r] = b3v;
            #pragma unroll
            for (int ks = 0; ks < 8; ++ks) {
                int kc = ks * 2 + lhalf;
                short8 a = *(const short8*)&h2s[kc * CH_STRIDE + (mt * 32 + l31) * 8];
                acc3 = __builtin_amdgcn_mfma_f32_32x32x16_bf16(a, w3f[ks], acc3, 0, 0, 0);
            }
            if (l31 < 4) {
                const int o = l31;
                float* op = out + ((size_t)((b << 2) + o) << 18) + ((size_t)i << 9);
                #pragma unroll
                for (int reg = 0; reg < 16; ++reg) {
                    int r = (reg & 3) + 8 * (reg >> 2) + 4 * lhalf;
                    op[jbase + mt * 32 + r] = acc3[reg];
                }
            }
        }
        // no trailing barrier needed: next phase A writes ash (reads of ash ended before S2),
        // and next phase C's h2s writes are fenced by the next S1.
    }
}

extern "C" void kernel_launch(void* const* d_in, const int* in_sizes, int n_in,
                              void* d_out, int out_size, void* d_ws, size_t ws_size,
                              hipStream_t stream) {
    const float* gq  = (const float*)d_in[0];
    const float* gkv = (const float*)d_in[1];
    const float* W1  = (const float*)d_in[2];
    const float* b1  = (const float*)d_in[3];
    const float* W2  = (const float*)d_in[4];
    const float* b2  = (const float*)d_in[5];
    const float* W3  = (const float*)d_in[6];
    const float* b3  = (const float*)d_in[7];
    float* out = (float*)d_out;

    crpb_mfma<<<NBLOCKS, 256, 0, stream>>>(gq, gkv, W1, b1, W2, b2, W3, b3, out);
}

// Round 3
// 156.201 us; speedup vs baseline: 2.8181x; 1.2147x over previous
//
#include <hip/hip_runtime.h>
#include <hip/hip_bf16.h>
#include <math.h>

// ---------------- problem constants ----------------
#define I_DIM 512
#define J_DIM 512
#define NDIM  128
#define TILE  64
#define NBLOCKS 1024
#define POS_PER_BLOCK 1024
#define ITERS 16                  // tiles per block
#define CH_STRIDE 520             // ushorts per k-chunk: 64 pos * 8 + 8 pad (keeps 16B align)

typedef __attribute__((ext_vector_type(8)))  short  short8;   // 8 bf16 (MFMA A/B frag)
typedef __attribute__((ext_vector_type(4)))  float  float4v;  // MFMA 16x16 C/D frag
typedef __attribute__((ext_vector_type(16))) float  float16;  // MFMA 32x32 C/D frag

// packed bf16 pair (RNE) -> one dword; v_cvt_pk_bf16_f32 on gfx950
__device__ __forceinline__ unsigned pk_bf16(float lo, float hi) {
    float2 t; t.x = lo; t.y = hi;
    __hip_bfloat162 r = __float22bfloat162_rn(t);
    unsigned u; __builtin_memcpy(&u, &r, 4);
    return u;
}

__global__ __launch_bounds__(256, 3)
void crpb_mfma2(const float* __restrict__ gq,   // (512,3)
                const float* __restrict__ gkv,  // (4,512,3)
                const float* __restrict__ W1,   // (3,128)
                const float* __restrict__ b1,   // (128,)
                const float* __restrict__ W2,   // (128,128)
                const float* __restrict__ b2,   // (128,)
                const float* __restrict__ W3,   // (128,4)
                const float* __restrict__ b3,   // (4,)
                float* __restrict__ out)        // (16,512,512)
{
    // h1 tile and h2 tile, both in chunked A/B-frag layout [kc][pos][8]
    __shared__ __align__(16) unsigned short ash[16 * CH_STRIDE];   // 16.6 KB
    __shared__ __align__(16) unsigned short h2s[16 * CH_STRIDE];   // 16.6 KB
    __shared__ __align__(16) float b2s[NDIM];

    const int tid   = threadIdx.x;
    const int lane  = tid & 63;
    const int w     = __builtin_amdgcn_readfirstlane(tid >> 6);  // force wave-uniform
    const int l31   = lane & 31;
    const int lhalf = lane >> 5;
    const int m16   = lane & 15;
    const int q16   = lane >> 4;

    if (tid < NDIM) b2s[tid] = b2[tid];

    // wave roles (layer-2, transposed: D = W2^T(A) x h1^T(B)):
    //   pos-tile pt = w&1 ; ch_out tiles ct0, ct0+1 = (w>>1)*2 + {0,1}
    const int pt  = w & 1;
    const int ct0 = (w >> 1) * 2;

    // ---- preload W2^T A-frags into registers (64 VGPRs) ----
    // a2f[ks] elem kk = W2T[ct*32+l31][16ks+8lhalf+kk] = W2[16ks+8lhalf+kk][ct*32+l31]
    short8 a2f0[8], a2f1[8];
    #pragma unroll
    for (int ks = 0; ks < 8; ++ks) {
        unsigned t0[4], t1[4];
        #pragma unroll
        for (int t = 0; t < 4; ++t) {
            const int d  = ks * 16 + lhalf * 8 + 2 * t;
            const int e0 = ct0 * 32 + l31;
            const int e1 = e0 + 32;
            t0[t] = pk_bf16(W2[d * 128 + e0], W2[(d + 1) * 128 + e0]);
            t1[t] = pk_bf16(W2[d * 128 + e1], W2[(d + 1) * 128 + e1]);
        }
        __builtin_memcpy(&a2f0[ks], t0, 16);
        __builtin_memcpy(&a2f1[ks], t1, 16);
    }

    // ---- preload W3^T A-frags for 16x16x32 phase D (16 VGPRs) ----
    // w3t[ks] elem kk = W3T[m16][32ks+8q16+kk] = W3[32ks+8q16+kk][m16] (m16>=4 -> 0)
    short8 w3t[4];
    #pragma unroll
    for (int ks = 0; ks < 4; ++ks) {
        unsigned tt[4];
        #pragma unroll
        for (int t = 0; t < 4; ++t) {
            const int k = ks * 32 + q16 * 8 + 2 * t;
            const float lo = (m16 < 4) ? W3[k * 4 + m16]       : 0.0f;
            const float hi = (m16 < 4) ? W3[(k + 1) * 4 + m16] : 0.0f;
            tt[t] = pk_bf16(lo, hi);
        }
        __builtin_memcpy(&w3t[ks], tt, 16);
    }
    float b3v[4];
    #pragma unroll
    for (int r = 0; r < 4; ++r) b3v[r] = (q16 == 0) ? b3[r] : 0.0f;   // row = q16*4+r = o

    __syncthreads();

    const int posblock = blockIdx.x * POS_PER_BLOCK;

    for (int it = 0; it < ITERS; ++it) {
        const int posbase = posblock + it * TILE;
        const int bb = posbase >> 18;
        const int i  = (posbase >> 9) & 511;
        const int jb = posbase & 511;

        // ======== phase A: per-lane features + layer 1 -> ash (frag layout) ========
        // lane owns position p = lane; wave owns channels w*32..w*32+31 (W1 wave-uniform)
        {
            const float q0 = gq[i * 3 + 0], q1 = gq[i * 3 + 1], q2 = gq[i * 3 + 2];
            const float* kvp = gkv + (size_t)(((bb << 9) + jb + lane)) * 3;
            const float d0 = q0 - kvp[0], d1 = q1 - kvp[1], d2 = q2 - kvp[2];
            // log1p(|x|) == log(1+|x|) exactly enough here (abs err ~6e-8)
            const float f0 = copysignf(__logf(1.0f + fabsf(d0)), d0);
            const float f1 = copysignf(__logf(1.0f + fabsf(d1)), d1);
            const float f2 = copysignf(__logf(1.0f + fabsf(d2)), d2);
            const int cbase = w * 32;
            #pragma unroll
            for (int qq = 0; qq < 4; ++qq) {
                unsigned pk[4];
                #pragma unroll
                for (int t = 0; t < 4; ++t) {
                    const int c = cbase + qq * 8 + 2 * t;
                    float h0 = fmaf(f2, W1[256 + c], fmaf(f1, W1[128 + c], fmaf(f0, W1[c], b1[c])));
                    float h1v = fmaf(f2, W1[256 + c + 1], fmaf(f1, W1[128 + c + 1], fmaf(f0, W1[c + 1], b1[c + 1])));
                    pk[t] = pk_bf16(fmaxf(h0, 0.0f), fmaxf(h1v, 0.0f));
                }
                short8 v; __builtin_memcpy(&v, pk, 16);
                *(short8*)&ash[(w * 4 + qq) * CH_STRIDE + lane * 8] = v;  // full-BW b128
            }
        }
        __syncthreads();   // S1: ash ready

        // ======== phase B: layer-2 MFMA, D[ch_out][pos], acc init = b2 ========
        float16 acc0, acc1;
        #pragma unroll
        for (int qr = 0; qr < 4; ++qr) {   // reg quad -> ch rows 8qr+4lhalf+{0..3}
            float4v i0 = *(const float4v*)&b2s[ct0 * 32 + 8 * qr + 4 * lhalf];
            float4v i1 = *(const float4v*)&b2s[(ct0 + 1) * 32 + 8 * qr + 4 * lhalf];
            #pragma unroll
            for (int t = 0; t < 4; ++t) { acc0[4 * qr + t] = i0[t]; acc1[4 * qr + t] = i1[t]; }
        }
        #pragma unroll
        for (int ks = 0; ks < 8; ++ks) {
            const int kc = ks * 2 + lhalf;
            short8 bfrag = *(const short8*)&ash[kc * CH_STRIDE + (pt * 32 + l31) * 8];
            acc0 = __builtin_amdgcn_mfma_f32_32x32x16_bf16(a2f0[ks], bfrag, acc0, 0, 0, 0);
            acc1 = __builtin_amdgcn_mfma_f32_32x32x16_bf16(a2f1[ks], bfrag, acc1, 0, 0, 0);
        }

        // ======== phase C: relu -> packed bf16 -> h2s (frag layout, b64 writes) ========
        #pragma unroll
        for (int qr = 0; qr < 4; ++qr) {
            // acc0: channels ct0*32 + 8qr + 4lhalf + {0..3} -> chunk ct0*4+qr, ush off 4lhalf
            uint2 u0, u1;
            u0.x = pk_bf16(fmaxf(acc0[4 * qr + 0], 0.f), fmaxf(acc0[4 * qr + 1], 0.f));
            u0.y = pk_bf16(fmaxf(acc0[4 * qr + 2], 0.f), fmaxf(acc0[4 * qr + 3], 0.f));
            u1.x = pk_bf16(fmaxf(acc1[4 * qr + 0], 0.f), fmaxf(acc1[4 * qr + 1], 0.f));
            u1.y = pk_bf16(fmaxf(acc1[4 * qr + 2], 0.f), fmaxf(acc1[4 * qr + 3], 0.f));
            *(uint2*)&h2s[(ct0 * 4 + qr) * CH_STRIDE + (pt * 32 + l31) * 8 + 4 * lhalf] = u0;
            *(uint2*)&h2s[((ct0 + 1) * 4 + qr) * CH_STRIDE + (pt * 32 + l31) * 8 + 4 * lhalf] = u1;
        }
        __syncthreads();   // S2: h2s ready

        // ======== phase D: layer-3 16x16x32 MFMA on ALL waves + coalesced store ========
        {
            float4v acc3;
            #pragma unroll
            for (int r = 0; r < 4; ++r) acc3[r] = b3v[r];
            #pragma unroll
            for (int ks = 0; ks < 4; ++ks) {
                const int kc = ks * 4 + q16;
                short8 bfrag = *(const short8*)&h2s[kc * CH_STRIDE + (w * 16 + m16) * 8];
                acc3 = __builtin_amdgcn_mfma_f32_16x16x32_bf16(w3t[ks], bfrag, acc3, 0, 0, 0);
            }
            // C/D: col = m16 = pos offset, row = q16*4 + r = o (valid o: q16==0)
            if (q16 == 0) {
                float* op = out + (((size_t)bb) << 20) + ((size_t)i << 9) + (jb + w * 16 + m16);
                #pragma unroll
                for (int r = 0; r < 4; ++r)
                    op[(size_t)r << 18] = acc3[r];
            }
        }
        // next phase A writes ash: safe — all waves' B-reads of ash finished before S2
    }
}

extern "C" void kernel_launch(void* const* d_in, const int* in_sizes, int n_in,
                              void* d_out, int out_size, void* d_ws, size_t ws_size,
                              hipStream_t stream) {
    const float* gq  = (const float*)d_in[0];
    const float* gkv = (const float*)d_in[1];
    const float* W1  = (const float*)d_in[2];
    const float* b1  = (const float*)d_in[3];
    const float* W2  = (const float*)d_in[4];
    const float* b2  = (const float*)d_in[5];
    const float* W3  = (const float*)d_in[6];
    const float* b3  = (const float*)d_in[7];
    float* out = (float*)d_out;

    crpb_mfma2<<<NBLOCKS, 256, 0, stream>>>(gq, gkv, W1, b1, W2, b2, W3, b3, out);
}

// Round 4
// 133.100 us; speedup vs baseline: 3.3072x; 1.1736x over previous
//
#include <hip/hip_runtime.h>
#include <math.h>

// ---------------- problem constants ----------------
#define NDIM 128
#define TILE 64
#define NBLOCKS 2048
#define POS_PER_BLOCK 512          // one full j-row per block: i, b constant
#define ITERS 8                    // tiles per block
#define CH 512                     // ushorts per k'-chunk: 64 pos * 8 (no pad; all ops b128)

typedef __attribute__((ext_vector_type(8)))  short  short8;   // MFMA A/B frag
typedef __attribute__((ext_vector_type(4)))  float  float4v;  // 16x16 C/D frag
typedef __attribute__((ext_vector_type(16))) float  float16;  // 32x32 C/D frag

// gfx950 packed f32x2 -> bf16x2 (RNE), single VALU instruction
__device__ __forceinline__ unsigned cvt_pk(float lo, float hi) {
    unsigned r;
    asm("v_cvt_pk_bf16_f32 %0, %1, %2" : "=v"(r) : "v"(lo), "v"(hi));
    return r;
}

// k'-space map: chunk c (0..15), elem jj (0..7) -> actual channel index.
// Chosen so one lane's 8 MFMA C-regs {4lh+0..3, 8+4lh+0..3} of a 32-ch block
// form one contiguous chunk -> phase A/C writes are single b128, conflict-free.
__device__ __forceinline__ int kmap(int c, int jj) {
    return 32 * (c >> 2) + 16 * ((c >> 1) & 1) + 4 * (c & 1) + ((jj >> 2) << 3) + (jj & 3);
}

__global__ __launch_bounds__(256, 3)
void crpb_mfma3(const float* __restrict__ gq,   // (512,3)
                const float* __restrict__ gkv,  // (4,512,3)
                const float* __restrict__ W1,   // (3,128)
                const float* __restrict__ b1,   // (128,)
                const float* __restrict__ W2,   // (128,128)
                const float* __restrict__ b2,   // (128,)
                const float* __restrict__ W3,   // (128,4)
                const float* __restrict__ b3,   // (4,)
                float* __restrict__ out)        // (16,512,512)
{
    __shared__ __align__(16) unsigned short ash[16 * CH];   // 16 KB: h1 tile, k'-chunked
    __shared__ __align__(16) unsigned short h2s[16 * CH];   // 16 KB: h2 tile, k'-chunked
    __shared__ __align__(16) float b2s[NDIM];

    const int tid   = threadIdx.x;
    const int lane  = tid & 63;
    const int w     = __builtin_amdgcn_readfirstlane(tid >> 6);
    const int l31   = lane & 31;
    const int lhalf = lane >> 5;
    const int m16   = lane & 15;
    const int q16   = lane >> 4;

    if (tid < NDIM) b2s[tid] = b2[tid];

    // wave roles: pos-tile pt = w&1; ch_out tiles ct0, ct0+1
    const int pt  = w & 1;
    const int ct0 = (w >> 1) * 2;

    // ---- preload W2^T A-frags (k'-permuted), 64 VGPRs ----
    short8 a2f0[8], a2f1[8];
    #pragma unroll
    for (int ks = 0; ks < 8; ++ks) {
        const int c = 2 * ks + lhalf;
        unsigned t0[4], t1[4];
        #pragma unroll
        for (int t = 0; t < 4; ++t) {
            const int d0 = kmap(c, 2 * t), d1 = d0 + 1;
            const int e0 = ct0 * 32 + l31, e1 = e0 + 32;
            t0[t] = cvt_pk(W2[d0 * 128 + e0], W2[d1 * 128 + e0]);
            t1[t] = cvt_pk(W2[d0 * 128 + e1], W2[d1 * 128 + e1]);
        }
        __builtin_memcpy(&a2f0[ks], t0, 16);
        __builtin_memcpy(&a2f1[ks], t1, 16);
    }

    // ---- preload W3^T A-frags (k'-permuted, N padded to 16), 16 VGPRs ----
    short8 w3t[4];
    #pragma unroll
    for (int ks = 0; ks < 4; ++ks) {
        const int c = ks * 4 + q16;
        unsigned tt[4];
        #pragma unroll
        for (int t = 0; t < 4; ++t) {
            const int k0 = kmap(c, 2 * t), k1 = k0 + 1;
            const float lo = (m16 < 4) ? W3[k0 * 4 + m16] : 0.0f;
            const float hi = (m16 < 4) ? W3[k1 * 4 + m16] : 0.0f;
            tt[t] = cvt_pk(lo, hi);
        }
        __builtin_memcpy(&w3t[ks], tt, 16);
    }
    float b3v[4];
    #pragma unroll
    for (int r = 0; r < 4; ++r) b3v[r] = (q16 == 0) ? b3[r] : 0.0f;

    __syncthreads();

    // block-constant indices: one j-row per block
    const int posblock = blockIdx.x * POS_PER_BLOCK;
    const int bb = posblock >> 18;
    const int i  = (posblock >> 9) & 511;
    const float q0 = gq[i * 3 + 0], q1 = gq[i * 3 + 1], q2 = gq[i * 3 + 2];

    // loop-invariant LDS bases (all accesses = base + immediate offset)
    unsigned short* aw        = ash + 4 * w * CH + lane * 8;                  // phase A writes
    const unsigned short* br  = ash + lhalf * CH + (pt * 32 + l31) * 8;       // phase B reads
    unsigned short* cw        = h2s + (ct0 * 4 + lhalf) * CH + (pt * 32 + l31) * 8; // C writes
    const unsigned short* dr  = h2s + q16 * CH + (w * 16 + m16) * 8;          // phase D reads

    const float* kvp0 = gkv + (size_t)((bb << 9) + lane) * 3;
    float* obase = out + (((size_t)bb) << 20) + ((size_t)i << 9) + w * 16 + m16;

    for (int it = 0; it < ITERS; ++it) {
        const int jb = it * TILE;

        // ======== phase A: features + layer 1 (VALU) -> ash, k'-chunked ========
        {
            const float* kvp = kvp0 + jb * 3;
            const float d0 = q0 - kvp[0], d1 = q1 - kvp[1], d2 = q2 - kvp[2];
            const float f0 = copysignf(__logf(1.0f + fabsf(d0)), d0);
            const float f1 = copysignf(__logf(1.0f + fabsf(d1)), d1);
            const float f2 = copysignf(__logf(1.0f + fabsf(d2)), d2);
            #pragma unroll
            for (int u = 0; u < 4; ++u) {
                const int c = 4 * w + u;
                unsigned pk[4];
                #pragma unroll
                for (int t = 0; t < 4; ++t) {
                    const int ch0 = kmap(c, 2 * t), ch1 = ch0 + 1;   // wave-uniform
                    float h0 = fmaf(f2, W1[256 + ch0], fmaf(f1, W1[128 + ch0],
                               fmaf(f0, W1[ch0], b1[ch0])));
                    float h1 = fmaf(f2, W1[256 + ch1], fmaf(f1, W1[128 + ch1],
                               fmaf(f0, W1[ch1], b1[ch1])));
                    pk[t] = cvt_pk(fmaxf(h0, 0.0f), fmaxf(h1, 0.0f));
                }
                short8 v; __builtin_memcpy(&v, pk, 16);
                *(short8*)(aw + u * CH) = v;        // b128, 16-B lane stride
            }
        }
        __syncthreads();   // S1: ash ready

        // ======== phase B: layer-2 MFMA (k'-consistent both sides) ========
        float16 acc0, acc1;
        #pragma unroll
        for (int qr = 0; qr < 4; ++qr) {
            float4v i0 = *(const float4v*)&b2s[ct0 * 32 + 8 * qr + 4 * lhalf];
            float4v i1 = *(const float4v*)&b2s[ct0 * 32 + 32 + 8 * qr + 4 * lhalf];
            #pragma unroll
            for (int t = 0; t < 4; ++t) { acc0[4 * qr + t] = i0[t]; acc1[4 * qr + t] = i1[t]; }
        }
        #pragma unroll
        for (int ks = 0; ks < 8; ++ks) {
            short8 bfrag = *(const short8*)(br + ks * 2 * CH);
            acc0 = __builtin_amdgcn_mfma_f32_32x32x16_bf16(a2f0[ks], bfrag, acc0, 0, 0, 0);
            acc1 = __builtin_amdgcn_mfma_f32_32x32x16_bf16(a2f1[ks], bfrag, acc1, 0, 0, 0);
        }

        // ======== phase C: relu -> packed bf16 -> h2s; 4x b128, conflict-free ========
        {
            unsigned p0[4], p1[4], p2[4], p3[4];
            #pragma unroll
            for (int t = 0; t < 4; ++t) {
                p0[t] = cvt_pk(fmaxf(acc0[2 * t], 0.f),     fmaxf(acc0[2 * t + 1], 0.f));
                p1[t] = cvt_pk(fmaxf(acc0[8 + 2 * t], 0.f), fmaxf(acc0[8 + 2 * t + 1], 0.f));
                p2[t] = cvt_pk(fmaxf(acc1[2 * t], 0.f),     fmaxf(acc1[2 * t + 1], 0.f));
                p3[t] = cvt_pk(fmaxf(acc1[8 + 2 * t], 0.f), fmaxf(acc1[8 + 2 * t + 1], 0.f));
            }
            short8 v0, v1, v2, v3;
            __builtin_memcpy(&v0, p0, 16); __builtin_memcpy(&v1, p1, 16);
            __builtin_memcpy(&v2, p2, 16); __builtin_memcpy(&v3, p3, 16);
            *(short8*)(cw + 0 * CH) = v0;   // chunk ct0*4 + lh      (regs 0-7)
            *(short8*)(cw + 2 * CH) = v1;   // chunk ct0*4 + 2 + lh  (regs 8-15)
            *(short8*)(cw + 4 * CH) = v2;   // acc1 likewise
            *(short8*)(cw + 6 * CH) = v3;
        }
        __syncthreads();   // S2: h2s ready (also fences this tile's ash reads)

        // ======== phase D: layer-3 16x16x32 MFMA + store ========
        {
            float4v acc3;
            #pragma unroll
            for (int r = 0; r < 4; ++r) acc3[r] = b3v[r];
            #pragma unroll
            for (int ks = 0; ks < 4; ++ks) {
                short8 bfrag = *(const short8*)(dr + ks * 4 * CH);
                acc3 = __builtin_amdgcn_mfma_f32_16x16x32_bf16(w3t[ks], bfrag, acc3, 0, 0, 0);
            }
            if (q16 == 0) {
                #pragma unroll
                for (int r = 0; r < 4; ++r)
                    obase[(size_t)(r << 18) + jb] = acc3[r];
            }
        }
        // next phase A overwrites ash (its reads ended before S2); D's h2s reads
        // complete before next S1, which fences the next phase C writes.
    }
}

extern "C" void kernel_launch(void* const* d_in, const int* in_sizes, int n_in,
                              void* d_out, int out_size, void* d_ws, size_t ws_size,
                              hipStream_t stream) {
    const float* gq  = (const float*)d_in[0];
    const float* gkv = (const float*)d_in[1];
    const float* W1  = (const float*)d_in[2];
    const float* b1  = (const float*)d_in[3];
    const float* W2  = (const float*)d_in[4];
    const float* b2  = (const float*)d_in[5];
    const float* W3  = (const float*)d_in[6];
    const float* b3  = (const float*)d_in[7];
    float* out = (float*)d_out;

    crpb_mfma3<<<NBLOCKS, 256, 0, stream>>>(gq, gkv, W1, b1, W2, b2, W3, b3, out);
}

// Round 5
// 127.227 us; speedup vs baseline: 3.4598x; 1.0462x over previous
//
#include <hip/hip_runtime.h>
#include <math.h>

// ---------------- problem constants ----------------
#define NDIM 128
#define TILE 64
#define NBLOCKS 2048
#define POS_PER_BLOCK 512          // one full j-row per block: i, b constant
#define ITERS 8                    // tiles per block
#define CH 512                     // ushorts per k'-chunk: 64 pos * 8 (no pad; all ops b128)

typedef __attribute__((ext_vector_type(8)))  short  short8;   // MFMA A/B frag
typedef __attribute__((ext_vector_type(4)))  float  float4v;  // 16x16 C/D frag
typedef __attribute__((ext_vector_type(16))) float  float16;  // 32x32 C/D frag

// gfx950 packed f32x2 -> bf16x2 (RNE), single VALU instruction
__device__ __forceinline__ unsigned cvt_pk(float lo, float hi) {
    unsigned r;
    asm("v_cvt_pk_bf16_f32 %0, %1, %2" : "=v"(r) : "v"(lo), "v"(hi));
    return r;
}

// k'-space map: chunk c (0..15), elem jj (0..7) -> actual channel index.
// One lane's 8 MFMA C-regs {4lh+0..3, 8+4lh+0..3} of a 32-ch tile form one
// contiguous chunk -> phase A/C writes are single b128, conflict-free.
__device__ __forceinline__ int kmap(int c, int jj) {
    return 32 * (c >> 2) + 16 * ((c >> 1) & 1) + 4 * (c & 1) + ((jj >> 2) << 3) + (jj & 3);
}

__global__ __launch_bounds__(256, 3)
void crpb_mfma4(const float* __restrict__ gq,   // (512,3)
                const float* __restrict__ gkv,  // (4,512,3)
                const float* __restrict__ W1,   // (3,128)
                const float* __restrict__ b1,   // (128,)
                const float* __restrict__ W2,   // (128,128)
                const float* __restrict__ b2,   // (128,)
                const float* __restrict__ W3,   // (128,4)
                const float* __restrict__ b3,   // (4,)
                float* __restrict__ out)        // (16,512,512)
{
    __shared__ __align__(16) unsigned short ash[16 * CH];   // 16 KB: h1 tile, k'-chunked
    __shared__ __align__(16) unsigned short h2s[16 * CH];   // 16 KB: h2 tile, k'-chunked
    __shared__ __align__(16) float b2s[NDIM];

    const int tid   = threadIdx.x;
    const int lane  = tid & 63;
    const int w     = __builtin_amdgcn_readfirstlane(tid >> 6);
    const int l31   = lane & 31;
    const int lhalf = lane >> 5;
    const int m16   = lane & 15;
    const int q16   = lane >> 4;

    if (tid < NDIM) b2s[tid] = b2[tid];

    // wave role: ONE out-ch tile ct = w, BOTH pos halves (32 W2-frag regs, 2 accs)
    const int ct = w;

    // ---- preload W2^T A-frags (k'-permuted), 32 VGPRs ----
    short8 a2f[8];
    #pragma unroll
    for (int ks = 0; ks < 8; ++ks) {
        const int c = 2 * ks + lhalf;
        unsigned t0[4];
        #pragma unroll
        for (int t = 0; t < 4; ++t) {
            const int d0 = kmap(c, 2 * t), d1 = d0 + 1;
            const int e0 = ct * 32 + l31;
            t0[t] = cvt_pk(W2[d0 * 128 + e0], W2[d1 * 128 + e0]);
        }
        __builtin_memcpy(&a2f[ks], t0, 16);
    }

    // ---- preload W3^T A-frags (k'-permuted, N padded to 16), 16 VGPRs ----
    short8 w3t[4];
    #pragma unroll
    for (int ks = 0; ks < 4; ++ks) {
        const int c = ks * 4 + q16;
        unsigned tt[4];
        #pragma unroll
        for (int t = 0; t < 4; ++t) {
            const int k0 = kmap(c, 2 * t), k1 = k0 + 1;
            const float lo = (m16 < 4) ? W3[k0 * 4 + m16] : 0.0f;
            const float hi = (m16 < 4) ? W3[k1 * 4 + m16] : 0.0f;
            tt[t] = cvt_pk(lo, hi);
        }
        __builtin_memcpy(&w3t[ks], tt, 16);
    }
    float b3v[4];
    #pragma unroll
    for (int r = 0; r < 4; ++r) b3v[r] = (q16 == 0) ? b3[r] : 0.0f;

    __syncthreads();

    // block-constant indices: one j-row per block
    const int posblock = blockIdx.x * POS_PER_BLOCK;
    const int bb = posblock >> 18;
    const int i  = (posblock >> 9) & 511;
    const float q0 = gq[i * 3 + 0], q1 = gq[i * 3 + 1], q2 = gq[i * 3 + 2];

    // loop-invariant LDS bases
    unsigned short* aw        = ash + 4 * w * CH + lane * 8;            // phase A writes
    const unsigned short* br  = ash + lhalf * CH + l31 * 8;             // phase B reads (pt0; pt1 = +256)
    unsigned short* cw        = h2s + (4 * ct + lhalf) * CH + l31 * 8;  // C writes (pt0; pt1 = +256)
    const unsigned short* dr  = h2s + q16 * CH + (w * 16 + m16) * 8;    // phase D reads

    const float* kvp0 = gkv + (size_t)((bb << 9) + lane) * 3;
    float* obase = out + (((size_t)bb) << 20) + ((size_t)i << 9) + w * 16 + m16;

    // prefetch first tile's kv
    float kv0 = kvp0[0], kv1 = kvp0[1], kv2 = kvp0[2];

    for (int it = 0; it < ITERS; ++it) {
        const int jb = it * TILE;

        // ======== phase A: features + layer 1 (VALU) -> ash, k'-chunked ========
        {
            const float d0 = q0 - kv0, d1 = q1 - kv1, d2 = q2 - kv2;
            // prefetch next tile's kv (wrap to 0 on last iter; always in-bounds)
            const float* kvn = kvp0 + ((it + 1) & 7) * (TILE * 3);
            kv0 = kvn[0]; kv1 = kvn[1]; kv2 = kvn[2];

            const float f0 = copysignf(__logf(1.0f + fabsf(d0)), d0);
            const float f1 = copysignf(__logf(1.0f + fabsf(d1)), d1);
            const float f2 = copysignf(__logf(1.0f + fabsf(d2)), d2);
            #pragma unroll
            for (int u = 0; u < 4; ++u) {
                const int c = 4 * w + u;
                unsigned pk[4];
                #pragma unroll
                for (int t = 0; t < 4; ++t) {
                    const int ch0 = kmap(c, 2 * t), ch1 = ch0 + 1;   // wave-uniform
                    float h0 = fmaf(f2, W1[256 + ch0], fmaf(f1, W1[128 + ch0],
                               fmaf(f0, W1[ch0], b1[ch0])));
                    float h1 = fmaf(f2, W1[256 + ch1], fmaf(f1, W1[128 + ch1],
                               fmaf(f0, W1[ch1], b1[ch1])));
                    pk[t] = cvt_pk(fmaxf(h0, 0.0f), fmaxf(h1, 0.0f));
                }
                short8 v; __builtin_memcpy(&v, pk, 16);
                *(short8*)(aw + u * CH) = v;        // b128, 16-B lane stride
            }
        }
        __syncthreads();   // S1: ash ready

        // ======== phase B: layer-2 MFMA; same ct, both pos halves ========
        float16 acc0, acc1;
        #pragma unroll
        for (int qr = 0; qr < 4; ++qr) {
            float4v i0 = *(const float4v*)&b2s[ct * 32 + 8 * qr + 4 * lhalf];
            #pragma unroll
            for (int t = 0; t < 4; ++t) { acc0[4 * qr + t] = i0[t]; acc1[4 * qr + t] = i0[t]; }
        }
        #pragma unroll
        for (int ks = 0; ks < 8; ++ks) {
            short8 bf0 = *(const short8*)(br + ks * 2 * CH);          // pos 0..31
            short8 bf1 = *(const short8*)(br + ks * 2 * CH + 256);    // pos 32..63
            acc0 = __builtin_amdgcn_mfma_f32_32x32x16_bf16(a2f[ks], bf0, acc0, 0, 0, 0);
            acc1 = __builtin_amdgcn_mfma_f32_32x32x16_bf16(a2f[ks], bf1, acc1, 0, 0, 0);
        }

        // ======== phase C: relu -> packed bf16 -> h2s; 4x b128, conflict-free ========
        {
            unsigned p0[4], p1[4], p2[4], p3[4];
            #pragma unroll
            for (int t = 0; t < 4; ++t) {
                p0[t] = cvt_pk(fmaxf(acc0[2 * t], 0.f),     fmaxf(acc0[2 * t + 1], 0.f));
                p1[t] = cvt_pk(fmaxf(acc0[8 + 2 * t], 0.f), fmaxf(acc0[8 + 2 * t + 1], 0.f));
                p2[t] = cvt_pk(fmaxf(acc1[2 * t], 0.f),     fmaxf(acc1[2 * t + 1], 0.f));
                p3[t] = cvt_pk(fmaxf(acc1[8 + 2 * t], 0.f), fmaxf(acc1[8 + 2 * t + 1], 0.f));
            }
            short8 v0, v1, v2, v3;
            __builtin_memcpy(&v0, p0, 16); __builtin_memcpy(&v1, p1, 16);
            __builtin_memcpy(&v2, p2, 16); __builtin_memcpy(&v3, p3, 16);
            *(short8*)(cw + 0 * CH) = v0;           // acc0 regs 0-7   (pos 0..31)
            *(short8*)(cw + 2 * CH) = v1;           // acc0 regs 8-15
            *(short8*)(cw + 0 * CH + 256) = v2;     // acc1 regs 0-7   (pos 32..63)
            *(short8*)(cw + 2 * CH + 256) = v3;     // acc1 regs 8-15
        }
        __syncthreads();   // S2: h2s ready (also fences this tile's ash reads)

        // ======== phase D: layer-3 16x16x32 MFMA + store ========
        {
            float4v acc3;
            #pragma unroll
            for (int r = 0; r < 4; ++r) acc3[r] = b3v[r];
            #pragma unroll
            for (int ks = 0; ks < 4; ++ks) {
                short8 bfrag = *(const short8*)(dr + ks * 4 * CH);
                acc3 = __builtin_amdgcn_mfma_f32_16x16x32_bf16(w3t[ks], bfrag, acc3, 0, 0, 0);
            }
            if (q16 == 0) {
                #pragma unroll
                for (int r = 0; r < 4; ++r)
                    obase[(size_t)(r << 18) + jb] = acc3[r];
            }
        }
        // next phase A overwrites ash (its reads ended before S2); D's h2s reads
        // complete before next S1, which fences the next phase C writes.
    }
}

extern "C" void kernel_launch(void* const* d_in, const int* in_sizes, int n_in,
                              void* d_out, int out_size, void* d_ws, size_t ws_size,
                              hipStream_t stream) {
    const float* gq  = (const float*)d_in[0];
    const float* gkv = (const float*)d_in[1];
    const float* W1  = (const float*)d_in[2];
    const float* b1  = (const float*)d_in[3];
    const float* W2  = (const float*)d_in[4];
    const float* b2  = (const float*)d_in[5];
    const float* W3  = (const float*)d_in[6];
    const float* b3  = (const float*)d_in[7];
    float* out = (float*)d_out;

    crpb_mfma4<<<NBLOCKS, 256, 0, stream>>>(gq, gkv, W1, b1, W2, b2, W3, b3, out);
}